// Round 7
// baseline (482.684 us; speedup 1.0000x reference)
//
#include <hip/hip_runtime.h>

#define NTAPS   63
#define NBATCH  32
#define SAMPLES 2097152
#define ROUT    16                      // outputs per thread
#define BLOCK   256
#define CHUNK   (ROUT * BLOCK)          // 4096 outputs per tile
#define NCHUNKS (SAMPLES / CHUNK)       // 512 tiles per batch row
#define ITERS   8                       // tiles per (persistent) block
#define NBLKX   (NCHUNKS / ITERS)       // 64 blocks per batch row
#define TILE_F  (CHUNK + 64)            // 4160 floats incl. 32/32 halo
#define TILE_B  (TILE_F / 4)            // 1040 float4 blocks
// pad one float4 slot per 4: conflict-free 80B-lane-stride window reads
#define PSLOT(o) ((o) + ((o) >> 2))
#define LDS_B   (PSLOT(TILE_B - 1) + 1) // 1299 float4 = 20784 B per buffer
#define TAIL_B  (TILE_B - 4 * BLOCK)    // 16

// Kernel 1: filt[b][t] = bias[t] + sum_k b[b][k] * W[t][k]   (b @ W.T + bias)
__global__ void filt_kernel(const float* __restrict__ b,
                            const float* __restrict__ W,
                            const float* __restrict__ bias,
                            float* __restrict__ filt) {
    const int batch = blockIdx.x;
    const int t = threadIdx.x;
    if (t < NTAPS) {
        const float* br = b + batch * NTAPS;
        const float* wr = W + t * NTAPS;
        float s = bias[t];
#pragma unroll
        for (int k = 0; k < NTAPS; ++k) s = fmaf(br[k], wr[k], s);
        filt[batch * NTAPS + t] = s;
    }
}

// Kernel 2: persistent-block, double-buffered LDS, pipelined FIR.
__global__ __launch_bounds__(BLOCK) void fir_kernel(const float* __restrict__ x,
                                                    const float* __restrict__ filt,
                                                    float* __restrict__ y) {
    __shared__ float4 tileA[LDS_B];
    __shared__ float4 tileB[LDS_B];

    const int tid   = threadIdx.x;
    const int batch = blockIdx.y;
    const int c0    = blockIdx.x * ITERS;            // first tile index of block
    const float* __restrict__ xb = x + (size_t)batch * SAMPLES;
    float*       __restrict__ yb = y + (size_t)batch * SAMPLES;
    const float* __restrict__ bf = filt + batch * NTAPS;   // uniform -> s_load

    float4 p0, p1, p2, p3, p4;                       // staging regs (T14)

    auto load_tile = [&](int c) {
        const int base = c * CHUNK - 32;
        if (c != 0 && c != NCHUNKS - 1) {            // interior: coalesced float4
            p0 = *reinterpret_cast<const float4*>(xb + base + 4 * (0 * BLOCK + tid));
            p1 = *reinterpret_cast<const float4*>(xb + base + 4 * (1 * BLOCK + tid));
            p2 = *reinterpret_cast<const float4*>(xb + base + 4 * (2 * BLOCK + tid));
            p3 = *reinterpret_cast<const float4*>(xb + base + 4 * (3 * BLOCK + tid));
            if (tid < TAIL_B)
                p4 = *reinterpret_cast<const float4*>(xb + base + 4 * (4 * BLOCK + tid));
        } else {                                     // edge: guarded, zero-pad
            float4* pr[5] = {&p0, &p1, &p2, &p3, &p4};
#pragma unroll
            for (int r = 0; r < 5; ++r) {
                const int o = r * BLOCK + tid;
                if (o < TILE_B) {
                    const int gi = base + 4 * o;
                    float4 v;
                    v.x = (gi + 0 >= 0 && gi + 0 < SAMPLES) ? xb[gi + 0] : 0.0f;
                    v.y = (gi + 1 >= 0 && gi + 1 < SAMPLES) ? xb[gi + 1] : 0.0f;
                    v.z = (gi + 2 >= 0 && gi + 2 < SAMPLES) ? xb[gi + 2] : 0.0f;
                    v.w = (gi + 3 >= 0 && gi + 3 < SAMPLES) ? xb[gi + 3] : 0.0f;
                    *pr[r] = v;
                }
            }
        }
    };

    auto store_tile = [&](float4* dst) {             // regs -> padded LDS
        dst[PSLOT(0 * BLOCK + tid)] = p0;
        dst[PSLOT(1 * BLOCK + tid)] = p1;
        dst[PSLOT(2 * BLOCK + tid)] = p2;
        dst[PSLOT(3 * BLOCK + tid)] = p3;
        if (tid < TAIL_B) dst[PSLOT(4 * BLOCK + tid)] = p4;
    };

    // prologue: tile c0 -> LDS A; loads for c0+1 left in flight across barrier
    load_tile(c0);
    store_tile(tileA);                               // compiler waits vmcnt for p*
    load_tile(c0 + 1);
    asm volatile("s_waitcnt lgkmcnt(0)" ::: "memory");
    __builtin_amdgcn_s_barrier();                    // raw: does NOT drain vmcnt

    float4* curT = tileA;
    float4* nxtT = tileB;

    for (int it = 0; it < ITERS; ++it) {
        // ---- compute tile (c0+it) from curT ----
        float w[80];                                 // compiler rolls liveness
#pragma unroll
        for (int j = 0; j < 20; ++j) {
            // PSLOT(4*tid + j) = 5*tid + j + (j>>2); lane stride 80 B: 32 banks even
            const float4 v = curT[5 * tid + j + (j >> 2)];
            w[4 * j + 0] = v.x;
            w[4 * j + 1] = v.y;
            w[4 * j + 2] = v.z;
            w[4 * j + 3] = v.w;
        }
        float acc[ROUT];
#pragma unroll
        for (int r = 0; r < ROUT; ++r) acc[r] = 0.0f;
#pragma unroll
        for (int t = 0; t < NTAPS; ++t) {
            const float c = bf[t];                   // SGPR
#pragma unroll
            for (int r = 0; r < ROUT; ++r) acc[r] = fmaf(c, w[r + t + 1], acc[r]);
        }
        const int s0 = (c0 + it) * CHUNK + tid * ROUT;
#pragma unroll
        for (int j = 0; j < 4; ++j) {
            float4 v;
            v.x = acc[4 * j + 0];
            v.y = acc[4 * j + 1];
            v.z = acc[4 * j + 2];
            v.w = acc[4 * j + 3];
            *reinterpret_cast<float4*>(yb + s0 + 4 * j) = v;
        }

        // ---- pipeline: stage tile (c0+it+1) into nxtT, issue loads (c0+it+2) ----
        if (it < ITERS - 1) {
            store_tile(nxtT);                        // vmcnt-waits only the p* loads
            if (it < ITERS - 2) load_tile(c0 + it + 2);  // in flight across barrier
            asm volatile("s_waitcnt lgkmcnt(0)" ::: "memory");
            __builtin_amdgcn_s_barrier();
            float4* tmp = curT; curT = nxtT; nxtT = tmp;
        }
    }
}

extern "C" void kernel_launch(void* const* d_in, const int* in_sizes, int n_in,
                              void* d_out, int out_size, void* d_ws, size_t ws_size,
                              hipStream_t stream) {
    const float* x    = (const float*)d_in[0];  // (32, 1, 2097152)
    const float* b    = (const float*)d_in[1];  // (32, 63)
    const float* W    = (const float*)d_in[2];  // (63, 63)
    const float* bias = (const float*)d_in[3];  // (63,)
    float* y = (float*)d_out;                   // (32, 1, 2097152)
    float* filt = (float*)d_ws;                 // 32*63 floats scratch

    filt_kernel<<<dim3(NBATCH), dim3(64), 0, stream>>>(b, W, bias, filt);

    dim3 grid(NBLKX, NBATCH);  // (64, 32) persistent blocks, 8 tiles each
    fir_kernel<<<grid, dim3(BLOCK), 0, stream>>>(x, filt, y);
}